// Round 10
// baseline (202.377 us; speedup 1.0000x reference)
//
#include <hip/hip_runtime.h>
#include <math.h>

// Problem constants (match reference setup_inputs()).
#define NG   256        // graphs
#define NP   256        // nodes per graph
#define NN   65536      // total nodes
#define NE   1048576    // edges
#define EPG  4096       // edges per graph
#define INF  16         // input feats
#define HID  64         // hidden
#define ZD   128        // latent dim
#define KFLAT 16384     // NP*HID

typedef _Float16 f16;
typedef f16  f16x8 __attribute__((ext_vector_type(8)));
typedef f16  f16x4 __attribute__((ext_vector_type(4)));
typedef float f32x4 __attribute__((ext_vector_type(4)));

#define XPCH 264  // LDS pitch (f16) for whole-graph 64x256 feature buffers
#define PCH  72   // LDS pitch (f16) for 64-wide staging tiles
#define APCH 260  // build accumulator pitch (f32): 4-bank row stride, no conflicts

// -------------- fused one-time casts/transposes (blockIdx ranges) ------------
// [0,128): small weights -> wb; [128,4224): Wmu|Wlv -> WT;
// [4224,6272): Wdec -> Wdecn (plain transpose, node-major columns).
__global__ __launch_bounds__(256) void k_prep(const float* __restrict__ W1,
                                              const float* __restrict__ W2,
                                              const float* __restrict__ W3,
                                              const float* __restrict__ W4,
                                              const float* __restrict__ Wg2,
                                              const float* __restrict__ Wg1,
                                              const float* __restrict__ Wmu,
                                              const float* __restrict__ Wlv,
                                              const float* __restrict__ Wdec,
                                              f16* __restrict__ wb,
                                              f16* __restrict__ WT,
                                              f16* __restrict__ Wdecn) {
    __shared__ float lsb[4 * 2080];                // 33.3 KB, shared by branches
    const int bx = blockIdx.x, t = threadIdx.x;
    if (bx < 128) {                                // ---- small weights
        int idx = bx * 256 + t;
        const float* srcp; int off, K2, srcK;
        if (idx < 2048)       { srcp = W1;  off = 0;     K2 = 32;  srcK = 16;  }
        else if (idx < 6144)  { srcp = W2;  off = 2048;  K2 = 64;  srcK = 64;  }
        else if (idx < 10240) { srcp = W3;  off = 6144;  K2 = 64;  srcK = 64;  }
        else if (idx < 14336) { srcp = W4;  off = 10240; K2 = 64;  srcK = 64;  }
        else if (idx < 18432) { srcp = Wg2; off = 14336; K2 = 64;  srcK = 64;  }
        else                  { srcp = Wg1; off = 18432; K2 = 224; srcK = 208; }
        int l = idx - off, of = l / K2, k = l % K2;
        wb[idx] = (k < srcK) ? (f16)srcp[k * 64 + of] : (f16)0.f;
    } else if (bx < 4224) {                        // ---- WT (Wmu|Wlv transposed)
        const int b2 = bx - 128;
        const int kt = b2 >> 3, jt = b2 & 7;
        const int k0 = kt * 32, j0 = (jt & 3) * 32;
        const float* Wsel = (jt < 4) ? Wmu : Wlv;
        const int jl = t & 31, kl0 = t >> 5;
        for (int p = 0; p < 4; ++p) {
            int kl = kl0 + p * 8;
            lsb[kl * 33 + jl] = Wsel[(size_t)(k0 + kl) * ZD + j0 + jl];
        }
        __syncthreads();
        const int kl2 = t & 31, jl0 = t >> 5;
        for (int p = 0; p < 4; ++p) {
            int jw = jl0 + p * 8;
            WT[(size_t)(jt * 32 + jw) * KFLAT + k0 + kl2] = (f16)lsb[kl2 * 33 + jw];
        }
    } else {                                       // ---- Wdecn transpose-cast
        const int b2 = bx - 4224;
        const int kt = b2 & 3, jt2 = b2 >> 2;      // 4 k-tiles x 512 jn-tiles
        const int k0 = kt * 32, jn0 = jt2 * 32;
        const int jl = t & 31, kl0 = t >> 5;
        for (int p = 0; p < 4; ++p) {
            int kl = kl0 + p * 8;
            lsb[kl * 33 + jl] = Wdec[(size_t)(k0 + kl) * KFLAT + jn0 + jl];
        }
        __syncthreads();
        const int kl2 = t & 31, jl0 = t >> 5;
        for (int p = 0; p < 4; ++p) {
            int jw = jl0 + p * 8;
            Wdecn[(size_t)(jn0 + jw) * ZD + k0 + kl2] = (f16)lsb[kl2 * 33 + jw];
        }
    }
}

// ---------- fused encoder: Ahat build + 4 GraphConvs in one kernel -----------
// Grid NG, 1024 thr. Build: 64-row chunks, pitch-260 f32 accumulator over XY.
// Ahat leaves the kernel ONLY as fragment-major AhatF (the bfrag dump — the
// block's threads collectively hold the full 256x256 Ahat). Conv weights
// staged ONCE into Ws4 so the per-conv Pt barrier (wave-private rows) can go:
// 1 barrier per conv instead of 2.
__global__ __launch_bounds__(1024) void k_enc(const int* __restrict__ src,
                                              const int* __restrict__ dst,
                                              const float* __restrict__ raw,
                                              const f16* __restrict__ wb,
                                              const float* __restrict__ b1,
                                              const float* __restrict__ b2,
                                              const float* __restrict__ b3,
                                              const float* __restrict__ b4,
                                              f16* __restrict__ AhatF,
                                              f16* __restrict__ h1b,
                                              f16* __restrict__ h3b,
                                              f16* __restrict__ h4b) {
    __shared__ __align__(16) f16 XY[2][64 * XPCH];   // 67.6 KB (build acc overlays)
    __shared__ __align__(16) f16 As[4][64 * PCH];    // 36.9 KB (build scratch / Pt)
    __shared__ f16 Ws4[4][64 * PCH];                 // 36.9 KB (all conv weights)
    __shared__ float bs4[4][64];
    const int g = blockIdx.x, t = threadIdx.x;
    const int wg = t >> 8, wl = (t >> 6) & 3;
    const int lane = t & 63, m16 = lane & 15, q = lane >> 4;
    // ---------------- Ahat build -------------
    float* acc_s = (float*)&XY[0][0];                        // 64*260*4 = 66560 B
    char*           scr2   = (char*)&As[0][0];
    unsigned short* eds    = (unsigned short*)scr2;          // 8192 B
    int*            cs_l   = (int*)(scr2 + 8192);            // 1024 B
    int*            cd_l   = (int*)(scr2 + 9216);
    float*          ns_l   = (float*)(scr2 + 10240);
    float*          nd_l   = (float*)(scr2 + 11264);         // ends 12288 <= 36864
    if (t < 256) { cs_l[t] = 0; cd_l[t] = 0; }
    __syncthreads();
    for (int i = t; i < EPG; i += 1024) {
        int s = src[g * EPG + i] & 255, d = dst[g * EPG + i] & 255;
        eds[i] = (unsigned short)((s << 8) | d);
        atomicAdd(&cs_l[s], 1);
        atomicAdd(&cd_l[d], 1);
    }
    // ---- stage ALL conv weights + biases (fenced by the next barrier) ----
    {
        const int woff[4] = {0, 2048, 6144, 10240};
        const float* bptr[4] = {b1, b2, b3, b4};
#pragma unroll
        for (int c = 0; c < 4; ++c) {
            const int K2 = (c == 0) ? 32 : 64;
            const f16* wt = wb + woff[c];
            for (int idx = t * 4; idx < 64 * K2; idx += 4096) {
                int of = idx / K2, k = idx % K2;
                *(f16x4*)&Ws4[c][of * PCH + k] = *(const f16x4*)&wt[of * K2 + k];
            }
            if (t < 64) bs4[c][t] = bptr[c][t];
        }
    }
    __syncthreads();
    if (t < 256) {
        ns_l[t] = rsqrtf((float)max(cs_l[t], 1));
        nd_l[t] = rsqrtf((float)max(cd_l[t], 1));
    }
    __syncthreads();
    const int myrow = wg * 64 + wl * 16 + m16;     // dst row owned by this thread
    f16x8 bfrag[8];
    for (int ch = 0; ch < 4; ++ch) {               // 64 dst rows per chunk
        for (int idx = t * 4; idx < 64 * APCH; idx += 4096)
            *(f32x4*)&acc_s[idx] = (f32x4){0.f, 0.f, 0.f, 0.f};
        __syncthreads();
        for (int i = t; i < EPG; i += 1024) {
            int e = eds[i], d = e & 255;
            if ((d >> 6) == ch) {
                int s = e >> 8;
                atomicAdd(&acc_s[(d & 63) * APCH + s], ns_l[s]);
            }
        }
        __syncthreads();
        if ((myrow >> 6) == ch) {                  // scatter my 64 cols to regs
            int dl = myrow & 63;
            float nd = nd_l[myrow];
#pragma unroll
            for (int kc = 0; kc < 4; ++kc)
#pragma unroll
                for (int ks = 0; ks < 2; ++ks) {
                    f16x8 v;
#pragma unroll
                    for (int j = 0; j < 8; ++j)
                        v[j] = (f16)(acc_s[dl * APCH + kc * 64 + ks * 32 + q * 8 + j] * nd);
                    bfrag[kc * 2 + ks] = v;
                }
        }
        __syncthreads();
    }
    // ---- dump bfrag -> AhatF (fragment-major; block covers full 256x256) ----
    {
        f16* ap = AhatF + ((size_t)g * 1024 + t) * 64;
#pragma unroll
        for (int i = 0; i < 8; ++i) *(f16x8*)&ap[i * 8] = bfrag[i];
    }
    // ---- raw -> XY[1] transpose (build acc region is dead now) ----
    {
        int n = t >> 2, f0 = (t & 3) * 4;
        float4 v4 = *(const float4*)&raw[((size_t)(g * 256 + n)) * 16 + f0];
        XY[1][(f0 + 0) * XPCH + n] = (f16)v4.x;
        XY[1][(f0 + 1) * XPCH + n] = (f16)v4.y;
        XY[1][(f0 + 2) * XPCH + n] = (f16)v4.z;
        XY[1][(f0 + 3) * XPCH + n] = (f16)v4.w;
    }
    __syncthreads();
    // ---------------- encoder convs (start cur=1: XY[1] holds rawT) ----------
    // 1 barrier per conv: Pt rows (wl*16+m16) are wave-private, Ws4/bs4 are
    // pre-staged, so write->read of Pt needs no block fence.
    int cur = 1;
#pragma unroll
    for (int c = 0; c < 4; ++c) {
        const int MT = (c == 0) ? 1 : 4;
        const int K2 = (c == 0) ? 32 : 64;
        // stage 1: agg^T = X^T . Ahat^T, B-operand entirely from registers.
        f32x4 acc1[4] = {};
#pragma unroll
        for (int kc = 0; kc < 4; ++kc)
#pragma unroll
            for (int ks = 0; ks < 2; ++ks) {
                f16x8 b = bfrag[kc * 2 + ks];
#pragma unroll
                for (int mt = 0; mt < MT; ++mt) {
                    f16x8 a = *(const f16x8*)&XY[cur][(mt * 16 + m16) * XPCH + kc * 64 + ks * 32 + q * 8];
                    acc1[mt] = __builtin_amdgcn_mfma_f32_16x16x32_f16(a, b, acc1[mt], 0, 0, 0);
                }
            }
        // stage 2: (agg)@W via Pt = As[wg], wave-private rows
        {
            f16* Pt = As[wg];
            if (MT == 1) {
                f16x4 z = {};
                *(f16x4*)&Pt[(wl * 16 + m16) * PCH + 16 + q * 4] = z;
            }
#pragma unroll
            for (int mt = 0; mt < MT; ++mt) {
                f16x4 v = {(f16)acc1[mt][0], (f16)acc1[mt][1],
                           (f16)acc1[mt][2], (f16)acc1[mt][3]};
                *(f16x4*)&Pt[(wl * 16 + m16) * PCH + mt * 16 + q * 4] = v;
            }
            // no barrier: same wave writes and reads rows wl*16+m16
            f32x4 acc2[4] = {};
#pragma unroll
            for (int ks = 0; ks < K2 / 32; ++ks) {
                f16x8 b = *(const f16x8*)&Pt[(wl * 16 + m16) * PCH + ks * 32 + q * 8];
#pragma unroll
                for (int mt = 0; mt < 4; ++mt) {
                    f16x8 a = *(const f16x8*)&Ws4[c][(mt * 16 + m16) * PCH + ks * 32 + q * 8];
                    acc2[mt] = __builtin_amdgcn_mfma_f32_16x16x32_f16(a, b, acc2[mt], 0, 0, 0);
                }
            }
            f16* Yf = XY[cur ^ 1];
#pragma unroll
            for (int mt = 0; mt < 4; ++mt)
#pragma unroll
                for (int r = 0; r < 4; ++r) {
                    int of = mt * 16 + q * 4 + r;
                    float v = fmaxf(acc2[mt][r] + bs4[c][of], 0.f);
                    Yf[of * XPCH + wg * 64 + wl * 16 + m16] = (f16)v;
                }
        }
        __syncthreads();
        cur ^= 1;
        const f16* Yv = XY[cur];
        // node-major outputs: [g*256+n][of] (transposed write, fully coalesced)
        if (c != 1) {
            f16* hb = (c == 0) ? h1b : (c == 2) ? h3b : h4b;
            int n = (t >> 2) & 255, of0 = (t & 3) * 16;
            f16x8 v0, v1;
            for (int i = 0; i < 8; ++i) v0[i] = Yv[(of0 + i) * XPCH + n];
            for (int i = 0; i < 8; ++i) v1[i] = Yv[(of0 + 8 + i) * XPCH + n];
            size_t base = ((size_t)(g * 256 + n)) * 64 + of0;
            *(f16x8*)&hb[base] = v0;
            *(f16x8*)&hb[base + 8] = v1;
        }
    }
}

// ------------------------------------- mu/logvar MFMA split-K GEMM -----------
// 32-way split-K. Grid 512 = 32kc x 4jt x 4gt.
#define BKP 136
__global__ __launch_bounds__(256) void k_mulv_mfma(const f16* __restrict__ h4b,
                                                   const f16* __restrict__ WT,
                                                   float* __restrict__ part) {
    __shared__ f16 Ab[64 * BKP];
    __shared__ f16 Bb[64 * BKP];
    const int bx = blockIdx.x;
    const int kc = bx & 31, jt = (bx >> 5) & 3, gt = bx >> 7;
    const int t = threadIdx.x;
    const int w = t >> 6, lane = t & 63;
    const int m16 = lane & 15, q = lane >> 4;
    f32x4 acc[4] = {};
    const int k0base = kc * 512;
    for (int ks = 0; ks < 4; ++ks) {
        const int k0 = k0base + ks * 128;
#pragma unroll
        for (int p = 0; p < 4; ++p) {
            int oct = t + p * 256;
            int r = oct >> 4, c8 = oct & 15;
            *(f16x8*)&Ab[r * BKP + c8 * 8] =
                *(const f16x8*)&h4b[(size_t)(gt * 64 + r) * KFLAT + k0 + c8 * 8];
            *(f16x8*)&Bb[r * BKP + c8 * 8] =
                *(const f16x8*)&WT[(size_t)(jt * 64 + r) * KFLAT + k0 + c8 * 8];
        }
        __syncthreads();
#pragma unroll
        for (int kk = 0; kk < 4; ++kk) {
            f16x8 a = *(const f16x8*)&Ab[(w * 16 + m16) * BKP + kk * 32 + q * 8];
#pragma unroll
            for (int nt = 0; nt < 4; ++nt) {
                f16x8 b = *(const f16x8*)&Bb[(nt * 16 + m16) * BKP + kk * 32 + q * 8];
                acc[nt] = __builtin_amdgcn_mfma_f32_16x16x32_f16(a, b, acc[nt], 0, 0, 0);
            }
        }
        __syncthreads();
    }
    const int pb = kc << 16;
#pragma unroll
    for (int nt = 0; nt < 4; ++nt) {
        const int jj = jt * 64 + nt * 16 + m16;
#pragma unroll
        for (int r = 0; r < 4; ++r) {
            int g = gt * 64 + w * 16 + q * 4 + r;
            part[pb + g * 256 + jj] = acc[nt][r];
        }
    }
}

// reduce partials -> mu, logvar (d_out) and z (f16).
__global__ __launch_bounds__(256) void k_reduce(const float* __restrict__ part,
                                                const float* __restrict__ bmu,
                                                const float* __restrict__ blv,
                                                const float* __restrict__ eps,
                                                float* __restrict__ out,
                                                f16* __restrict__ zb) {
    const int idx = blockIdx.x * 256 + threadIdx.x;
    const int g = idx >> 7, j = idx & 127;
    float mu = bmu[j], lv = blv[j];
    for (int kc = 0; kc < 32; ++kc) {
        mu += part[(kc << 16) + g * 256 + j];
        lv += part[(kc << 16) + g * 256 + 128 + j];
    }
    out[1048576 + idx] = mu;
    out[1048576 + 32768 + idx] = lv;
    zb[idx] = (f16)(mu + eps[idx] * expf(0.5f * lv));
}

// ------- latb[g*16384 + jn] = (z @ Wdec)[g][jn] + bdec[jn]  (node-major) -----
// Swapped operands: A = Wdecn rows (jn), B = z rows (g) -> lane-fast dim is jn
// -> contiguous f16x4 stores. Grid 512 = 4gt x 128 jn-tiles.
#define DKP 136
__global__ __launch_bounds__(256) void k_decgemm(const f16* __restrict__ zb,
                                                 const f16* __restrict__ Wdecn,
                                                 const float* __restrict__ bdec,
                                                 f16* __restrict__ latb) {
    __shared__ f16 Wn[128 * DKP];
    __shared__ f16 Zt[64 * DKP];
    const int gt = blockIdx.x >> 7, jt = blockIdx.x & 127;
    const int t = threadIdx.x, w = t >> 6, lane = t & 63, m16 = lane & 15, q = lane >> 4;
    for (int idx = t * 8; idx < 128 * 128; idx += 2048) {
        int r = idx >> 7, c = idx & 127;
        *(f16x8*)&Wn[r * DKP + c] = *(const f16x8*)&Wdecn[((size_t)(jt * 128 + r)) * ZD + c];
    }
    for (int idx = t * 8; idx < 64 * 128; idx += 2048) {
        int r = idx >> 7, c = idx & 127;
        *(f16x8*)&Zt[r * DKP + c] = *(const f16x8*)&zb[(gt * 64 + r) * ZD + c];
    }
    __syncthreads();
    f32x4 acc[2][4] = {};
#pragma unroll
    for (int kk = 0; kk < 4; ++kk) {
        f16x8 a0 = *(const f16x8*)&Wn[(w * 32 + m16) * DKP + kk * 32 + q * 8];
        f16x8 a1 = *(const f16x8*)&Wn[(w * 32 + 16 + m16) * DKP + kk * 32 + q * 8];
#pragma unroll
        for (int nt = 0; nt < 4; ++nt) {
            f16x8 b = *(const f16x8*)&Zt[(nt * 16 + m16) * DKP + kk * 32 + q * 8];
            acc[0][nt] = __builtin_amdgcn_mfma_f32_16x16x32_f16(a0, b, acc[0][nt], 0, 0, 0);
            acc[1][nt] = __builtin_amdgcn_mfma_f32_16x16x32_f16(a1, b, acc[1][nt], 0, 0, 0);
        }
    }
#pragma unroll
    for (int mi = 0; mi < 2; ++mi) {
        int jn0 = jt * 128 + w * 32 + mi * 16 + q * 4;
        float4 bd = *(const float4*)&bdec[jn0];
#pragma unroll
        for (int nt = 0; nt < 4; ++nt) {
            int g = gt * 64 + nt * 16 + m16;
            f16x4 v = {(f16)(acc[mi][nt][0] + bd.x), (f16)(acc[mi][nt][1] + bd.y),
                       (f16)(acc[mi][nt][2] + bd.z), (f16)(acc[mi][nt][3] + bd.w)};
            *(f16x4*)&latb[(size_t)g * KFLAT + jn0] = v;
        }
    }
}

// ----------------- fused decoder: catgemm, g1, g2, out GEMM ------------------
#define WPCH 240   // Wg1s pitch (f16): 480 B rows, 16B-aligned fragments
__global__ __launch_bounds__(1024) void k_decfused(const f16* __restrict__ latb,
                                                   const f16* __restrict__ h1b,
                                                   const f16* __restrict__ h3b,
                                                   const f16* __restrict__ AhatF,
                                                   const f16* __restrict__ wb,
                                                   const float* __restrict__ bg1,
                                                   const float* __restrict__ bg2,
                                                   const float* __restrict__ Wout,
                                                   const float* __restrict__ bout,
                                                   const float* __restrict__ raw,
                                                   float* __restrict__ out) {
    __shared__ f16 XY[2][64 * XPCH];   // 67.6 KB
    __shared__ f16 As[4][64 * PCH];    // 36.9 KB, used only as Pt
    __shared__ f16 Ws[64 * PCH];       // 9.2 KB (Wg2)
    __shared__ f16 Wg1s[64 * WPCH];    // 30 KB (whole Wg1^T, staged once)
    __shared__ float WL[1024];
    __shared__ float bs1[64], bs2[64];
    const int g = blockIdx.x, t = threadIdx.x;
    const int wg = t >> 8, wl = (t >> 6) & 3;
    const int lane = t & 63, m16 = lane & 15, q = lane >> 4;
    const int n = wg * 64 + wl * 16 + m16;         // output node owned (B-col)
    const f16* wg1t = wb + 18432;
    const f16* wg2t = wb + 14336;
    // register-resident Ahat B-fragments (fragment-major AhatF: 128 B/thread,
    // perfectly coalesced; layout matches k_enc's bfrag dump exactly).
    f16x8 bfrag[8];
    {
        const f16* ap = AhatF + ((size_t)g * 1024 + t) * 64;
#pragma unroll
        for (int i = 0; i < 8; ++i) bfrag[i] = *(const f16x8*)&ap[i * 8];
    }
    // cat^T B-fragments: node-major buffers -> each octet is ONE f16x8 load.
    const size_t nb = (size_t)(g * 256 + n);
    f16x8 bcat[7];
#pragma unroll
    for (int kc = 0; kc < 7; ++kc) {
        int k0 = kc * 32 + q * 8;
        f16x8 v = {};
        if (k0 < 64) {
            v = *(const f16x8*)&latb[nb * 64 + k0];
        } else if (k0 < 80) {
            const float* rpf = raw + nb * 16 + (k0 - 64);
#pragma unroll
            for (int i = 0; i < 8; ++i) v[i] = (f16)rpf[i];
        } else if (k0 < 144) {
            v = *(const f16x8*)&h1b[nb * 64 + (k0 - 80)];
        } else if (k0 < 208) {
            v = *(const f16x8*)&h3b[nb * 64 + (k0 - 144)];
        }
        bcat[kc] = v;
    }
    if (t < 64) bs1[t] = bg1[t];
    else if (t < 128) bs2[t - 64] = bg2[t - 64];
    // ---- phase 1: t^T = Wg1t . cat^T -> XY[0] (1 barrier, B from registers)
    // (Wg2 -> Ws staged here too, so phase 3 needs no staging barrier.)
    {
        for (int idx = t; idx < 3584; idx += 1024) {       // 64 rows x 56 segs
            int of = idx / 56, sg = idx % 56;
            *(f16x4*)&Wg1s[of * WPCH + sg * 4] = *(const f16x4*)&wg1t[of * 224 + sg * 4];
        }
        for (int idx = t * 4; idx < 4096; idx += 4096) {
            int of = idx >> 6, k = idx & 63;
            *(f16x4*)&Ws[of * PCH + k] = *(const f16x4*)&wg2t[of * 64 + k];
        }
        __syncthreads();
        f32x4 acc[4] = {};
#pragma unroll
        for (int kc = 0; kc < 7; ++kc) {
            f16x8 b = bcat[kc];
#pragma unroll
            for (int mt = 0; mt < 4; ++mt) {
                f16x8 a = *(const f16x8*)&Wg1s[(mt * 16 + m16) * WPCH + kc * 32 + q * 8];
                acc[mt] = __builtin_amdgcn_mfma_f32_16x16x32_f16(a, b, acc[mt], 0, 0, 0);
            }
        }
#pragma unroll
        for (int mt = 0; mt < 4; ++mt)
#pragma unroll
            for (int r = 0; r < 4; ++r)
                XY[0][(mt * 16 + q * 4 + r) * XPCH + n] = (f16)acc[mt][r];
        __syncthreads();
    }
    // ---- phase 2: x1 = relu(Ahat @ t + bg1) -> XY[1] (B from registers)
    {
        f32x4 acc1[4] = {};
#pragma unroll
        for (int kc = 0; kc < 4; ++kc)
#pragma unroll
            for (int ks = 0; ks < 2; ++ks) {
                f16x8 b = bfrag[kc * 2 + ks];
#pragma unroll
                for (int mt = 0; mt < 4; ++mt) {
                    f16x8 a = *(const f16x8*)&XY[0][(mt * 16 + m16) * XPCH + kc * 64 + ks * 32 + q * 8];
                    acc1[mt] = __builtin_amdgcn_mfma_f32_16x16x32_f16(a, b, acc1[mt], 0, 0, 0);
                }
            }
#pragma unroll
        for (int mt = 0; mt < 4; ++mt)
#pragma unroll
            for (int r = 0; r < 4; ++r) {
                int of = mt * 16 + q * 4 + r;
                float v = fmaxf(acc1[mt][r] + bs1[of], 0.f);
                XY[1][of * XPCH + n] = (f16)v;
            }
        __syncthreads();
    }
    // ---- phase 3: x2 = relu((Ahat @ x1)@Wg2 + bg2) -> XY[0]
    {
        f32x4 acc1[4] = {};
#pragma unroll
        for (int kc = 0; kc < 4; ++kc)
#pragma unroll
            for (int ks = 0; ks < 2; ++ks) {
                f16x8 b = bfrag[kc * 2 + ks];
#pragma unroll
                for (int mt = 0; mt < 4; ++mt) {
                    f16x8 a = *(const f16x8*)&XY[1][(mt * 16 + m16) * XPCH + kc * 64 + ks * 32 + q * 8];
                    acc1[mt] = __builtin_amdgcn_mfma_f32_16x16x32_f16(a, b, acc1[mt], 0, 0, 0);
                }
            }
        f16* Pt = As[wg];
#pragma unroll
        for (int mt = 0; mt < 4; ++mt) {
            f16x4 v = {(f16)acc1[mt][0], (f16)acc1[mt][1],
                       (f16)acc1[mt][2], (f16)acc1[mt][3]};
            *(f16x4*)&Pt[(wl * 16 + m16) * PCH + mt * 16 + q * 4] = v;
        }
        // no barrier: Pt rows wl*16+m16 are wave-private; Ws pre-staged.
        f32x4 acc2[4] = {};
#pragma unroll
        for (int ks = 0; ks < 2; ++ks) {
            f16x8 b = *(const f16x8*)&Pt[(wl * 16 + m16) * PCH + ks * 32 + q * 8];
#pragma unroll
            for (int mt = 0; mt < 4; ++mt) {
                f16x8 a = *(const f16x8*)&Ws[(mt * 16 + m16) * PCH + ks * 32 + q * 8];
                acc2[mt] = __builtin_amdgcn_mfma_f32_16x16x32_f16(a, b, acc2[mt], 0, 0, 0);
            }
        }
#pragma unroll
        for (int mt = 0; mt < 4; ++mt)
#pragma unroll
            for (int r = 0; r < 4; ++r) {
                int of = mt * 16 + q * 4 + r;
                float v = fmaxf(acc2[mt][r] + bs2[of], 0.f);
                XY[0][of * XPCH + n] = (f16)v;
            }
        __syncthreads();
    }
    // ---- phase 4: recon = x2^T @ Wout + bout (col0 = raw)
    {
        WL[t & 1023] = Wout[t & 1023];
        __syncthreads();
        int nn = t & 255, og = t >> 8;
        float acc4[4];
        for (int j = 0; j < 4; ++j) acc4[j] = bout[og * 4 + j];
#pragma unroll 4
        for (int f = 0; f < 64; ++f) {
            float xv = (float)XY[0][f * XPCH + nn];
            for (int j = 0; j < 4; ++j) acc4[j] += xv * WL[f * 16 + og * 4 + j];
        }
        size_t ob = ((size_t)(g * 256 + nn)) * 16 + og * 4;
        if (og == 0) acc4[0] = raw[((size_t)(g * 256 + nn)) * 16];
        *(float4*)&out[ob] = make_float4(acc4[0], acc4[1], acc4[2], acc4[3]);
    }
}

// ----------------------------------------------------------------- launch ----
extern "C" void kernel_launch(void* const* d_in, const int* in_sizes, int n_in,
                              void* d_out, int out_size, void* d_ws, size_t ws_size,
                              hipStream_t stream) {
    const float* raw  = (const float*)d_in[0];
    const int*   src  = (const int*)d_in[1];
    const int*   dst  = (const int*)d_in[2];
    const float* eps  = (const float*)d_in[3];
    const float* W1   = (const float*)d_in[4];
    const float* b1   = (const float*)d_in[5];
    const float* W2   = (const float*)d_in[6];
    const float* b2   = (const float*)d_in[7];
    const float* W3   = (const float*)d_in[8];
    const float* b3   = (const float*)d_in[9];
    const float* W4   = (const float*)d_in[10];
    const float* b4   = (const float*)d_in[11];
    const float* Wmu  = (const float*)d_in[12];
    const float* bmu  = (const float*)d_in[13];
    const float* Wlv  = (const float*)d_in[14];
    const float* blv  = (const float*)d_in[15];
    const float* Wdec = (const float*)d_in[16];
    const float* bdec = (const float*)d_in[17];
    const float* Wg1  = (const float*)d_in[18];
    const float* bg1  = (const float*)d_in[19];
    const float* Wg2  = (const float*)d_in[20];
    const float* bg2  = (const float*)d_in[21];
    const float* Wout = (const float*)d_in[22];
    const float* bout = (const float*)d_in[23];
    float* out = (float*)d_out;

    // workspace carve-up (~85 MB)
    char* p = (char*)d_ws;
    f16* AhatF = (f16*)p;             p += (size_t)NG * 1024 * 64 * 2;   // 32 MB
    f16* WT    = (f16*)p;             p += (size_t)256 * KFLAT * 2;      // 8 MB
    f16* Wdecn = (f16*)p;             p += (size_t)KFLAT * ZD * 2;       // 4 MB
    f16* wb    = (f16*)p;             p += 65536;                        // 64 KB
    f16* zb    = (f16*)p;             p += 65536;                        // 64 KB
    f16* h1b   = (f16*)p;             p += (size_t)NN * 64 * 2;          // 8 MB
    f16* h3b   = (f16*)p;             p += (size_t)NN * 64 * 2;
    f16* h4b   = (f16*)p;             p += (size_t)NN * 64 * 2;
    f16* latb  = (f16*)p;             p += (size_t)NN * 64 * 2;
    float* part = (float*)p;          p += (size_t)32 * 65536 * 4;       // 8 MB

    // one-time weight casts/transposes
    k_prep<<<6272, 256, 0, stream>>>(W1, W2, W3, W4, Wg2, Wg1, Wmu, Wlv, Wdec,
                                     wb, WT, Wdecn);

    // encoder (1 launch: Ahat build + raw transpose + conv1..conv4)
    k_enc<<<NG, 1024, 0, stream>>>(src, dst, raw, wb, b1, b2, b3, b4,
                                   AhatF, h1b, h3b, h4b);

    // bottleneck: mu/logvar -> z -> latent
    k_mulv_mfma<<<512, 256, 0, stream>>>(h4b, WT, part);
    k_reduce<<<128, 256, 0, stream>>>(part, bmu, blv, eps, out, zb);
    k_decgemm<<<512, 256, 0, stream>>>(zb, Wdecn, bdec, latb);

    // decoder (1 launch: catgemm + g1 + g2 + out GEMM fused)
    k_decfused<<<NG, 1024, 0, stream>>>(latb, h1b, h3b, AhatF, wb,
                                        bg1, bg2, Wout, bout, raw, out);
}

// Round 11
// 191.847 us; speedup vs baseline: 1.0549x; 1.0549x over previous
//
#include <hip/hip_runtime.h>
#include <math.h>

// Problem constants (match reference setup_inputs()).
#define NG   256        // graphs
#define NP   256        // nodes per graph
#define NN   65536      // total nodes
#define NE   1048576    // edges
#define EPG  4096       // edges per graph
#define INF  16         // input feats
#define HID  64         // hidden
#define ZD   128        // latent dim
#define KFLAT 16384     // NP*HID

typedef _Float16 f16;
typedef f16  f16x8 __attribute__((ext_vector_type(8)));
typedef f16  f16x4 __attribute__((ext_vector_type(4)));
typedef float f32x4 __attribute__((ext_vector_type(4)));

#define XPCH 264  // LDS pitch (f16) for whole-graph 64x256 feature buffers
#define PCH  72   // LDS pitch (f16) for 64-wide staging tiles
#define APCH 260  // build accumulator pitch (f32): 4-bank row stride, no conflicts

// -------------- fused one-time casts/transposes (blockIdx ranges) ------------
// [0,128): small weights -> wb; [128,4224): Wmu|Wlv -> WT;
// [4224,6272): Wdec -> Wdecn (plain transpose, node-major columns).
__global__ __launch_bounds__(256) void k_prep(const float* __restrict__ W1,
                                              const float* __restrict__ W2,
                                              const float* __restrict__ W3,
                                              const float* __restrict__ W4,
                                              const float* __restrict__ Wg2,
                                              const float* __restrict__ Wg1,
                                              const float* __restrict__ Wmu,
                                              const float* __restrict__ Wlv,
                                              const float* __restrict__ Wdec,
                                              f16* __restrict__ wb,
                                              f16* __restrict__ WT,
                                              f16* __restrict__ Wdecn) {
    __shared__ float lsb[4 * 2080];                // 33.3 KB, shared by branches
    const int bx = blockIdx.x, t = threadIdx.x;
    if (bx < 128) {                                // ---- small weights
        int idx = bx * 256 + t;
        const float* srcp; int off, K2, srcK;
        if (idx < 2048)       { srcp = W1;  off = 0;     K2 = 32;  srcK = 16;  }
        else if (idx < 6144)  { srcp = W2;  off = 2048;  K2 = 64;  srcK = 64;  }
        else if (idx < 10240) { srcp = W3;  off = 6144;  K2 = 64;  srcK = 64;  }
        else if (idx < 14336) { srcp = W4;  off = 10240; K2 = 64;  srcK = 64;  }
        else if (idx < 18432) { srcp = Wg2; off = 14336; K2 = 64;  srcK = 64;  }
        else                  { srcp = Wg1; off = 18432; K2 = 224; srcK = 208; }
        int l = idx - off, of = l / K2, k = l % K2;
        wb[idx] = (k < srcK) ? (f16)srcp[k * 64 + of] : (f16)0.f;
    } else if (bx < 4224) {                        // ---- WT (Wmu|Wlv transposed)
        const int b2 = bx - 128;
        const int kt = b2 >> 3, jt = b2 & 7;
        const int k0 = kt * 32, j0 = (jt & 3) * 32;
        const float* Wsel = (jt < 4) ? Wmu : Wlv;
        const int jl = t & 31, kl0 = t >> 5;
        for (int p = 0; p < 4; ++p) {
            int kl = kl0 + p * 8;
            lsb[kl * 33 + jl] = Wsel[(size_t)(k0 + kl) * ZD + j0 + jl];
        }
        __syncthreads();
        const int kl2 = t & 31, jl0 = t >> 5;
        for (int p = 0; p < 4; ++p) {
            int jw = jl0 + p * 8;
            WT[(size_t)(jt * 32 + jw) * KFLAT + k0 + kl2] = (f16)lsb[kl2 * 33 + jw];
        }
    } else {                                       // ---- Wdecn transpose-cast
        const int b2 = bx - 4224;
        const int kt = b2 & 3, jt2 = b2 >> 2;      // 4 k-tiles x 512 jn-tiles
        const int k0 = kt * 32, jn0 = jt2 * 32;
        const int jl = t & 31, kl0 = t >> 5;
        for (int p = 0; p < 4; ++p) {
            int kl = kl0 + p * 8;
            lsb[kl * 33 + jl] = Wdec[(size_t)(k0 + kl) * KFLAT + jn0 + jl];
        }
        __syncthreads();
        const int kl2 = t & 31, jl0 = t >> 5;
        for (int p = 0; p < 4; ++p) {
            int jw = jl0 + p * 8;
            Wdecn[(size_t)(jn0 + jw) * ZD + k0 + kl2] = (f16)lsb[kl2 * 33 + jw];
        }
    }
}

// ---------- fused encoder: Ahat build + 4 GraphConvs in one kernel -----------
// Grid NG, 1024 thr. Build: 64-row chunks, f32 accumulator (pitch 260 ->
// conflict-free scatter) over the XY region, predicated edge re-scan.
// raw transpose runs AFTER the build. Outputs node-major.
__global__ __launch_bounds__(1024) void k_enc(const int* __restrict__ src,
                                              const int* __restrict__ dst,
                                              const float* __restrict__ raw,
                                              const f16* __restrict__ wb,
                                              const float* __restrict__ b1,
                                              const float* __restrict__ b2,
                                              const float* __restrict__ b3,
                                              const float* __restrict__ b4,
                                              f16* __restrict__ Ahat,
                                              f16* __restrict__ h1b,
                                              f16* __restrict__ h3b,
                                              f16* __restrict__ h4b) {
    __shared__ __align__(16) f16 XY[2][64 * XPCH];   // 67.6 KB (build acc overlays)
    __shared__ __align__(16) f16 As[4][64 * PCH];    // 36.9 KB (build scratch / Pt)
    __shared__ f16 Ws[64 * PCH];
    __shared__ float bs[64];
    const int g = blockIdx.x, t = threadIdx.x;
    const int wg = t >> 8, tl = t & 255, wl = (t >> 6) & 3;
    const int lane = t & 63, m16 = lane & 15, q = lane >> 4;
    // ---------------- Ahat build -------------
    float* acc_s = (float*)&XY[0][0];                        // 64*260*4 = 66560 B
    char*           scr2   = (char*)&As[0][0];
    unsigned short* eds    = (unsigned short*)scr2;          // 8192 B
    int*            cs_l   = (int*)(scr2 + 8192);            // 1024 B
    int*            cd_l   = (int*)(scr2 + 9216);
    float*          ns_l   = (float*)(scr2 + 10240);
    float*          nd_l   = (float*)(scr2 + 11264);         // ends 12288 <= 36864
    if (t < 256) { cs_l[t] = 0; cd_l[t] = 0; }
    __syncthreads();
    for (int i = t; i < EPG; i += 1024) {
        int s = src[g * EPG + i] & 255, d = dst[g * EPG + i] & 255;
        eds[i] = (unsigned short)((s << 8) | d);
        atomicAdd(&cs_l[s], 1);
        atomicAdd(&cd_l[d], 1);
    }
    __syncthreads();
    if (t < 256) {
        ns_l[t] = rsqrtf((float)max(cs_l[t], 1));
        nd_l[t] = rsqrtf((float)max(cd_l[t], 1));
    }
    __syncthreads();
    const int myrow = wg * 64 + wl * 16 + m16;     // dst row owned by this thread
    f16x8 bfrag[8];
    for (int ch = 0; ch < 4; ++ch) {               // 64 dst rows per chunk
        for (int idx = t * 4; idx < 64 * APCH; idx += 4096)
            *(f32x4*)&acc_s[idx] = (f32x4){0.f, 0.f, 0.f, 0.f};
        __syncthreads();
        for (int i = t; i < EPG; i += 1024) {
            int e = eds[i], d = e & 255;
            if ((d >> 6) == ch) {
                int s = e >> 8;
                atomicAdd(&acc_s[(d & 63) * APCH + s], ns_l[s]);
            }
        }
        __syncthreads();
#pragma unroll
        for (int p = 0; p < 2; ++p) {
            int idx = t + p * 1024;
            int dl = idx >> 5, s0 = (idx & 31) * 8;
            float nd = nd_l[ch * 64 + dl];
            f16x8 v;
            for (int j = 0; j < 8; ++j) v[j] = (f16)(acc_s[dl * APCH + s0 + j] * nd);
            *(f16x8*)&Ahat[(((size_t)(g * 256 + ch * 64 + dl)) << 8) | s0] = v;
        }
        if ((myrow >> 6) == ch) {                  // scatter my 64 cols to regs
            int dl = myrow & 63;
            float nd = nd_l[myrow];
#pragma unroll
            for (int kc = 0; kc < 4; ++kc)
#pragma unroll
                for (int ks = 0; ks < 2; ++ks) {
                    f16x8 v;
#pragma unroll
                    for (int j = 0; j < 8; ++j)
                        v[j] = (f16)(acc_s[dl * APCH + kc * 64 + ks * 32 + q * 8 + j] * nd);
                    bfrag[kc * 2 + ks] = v;
                }
        }
        __syncthreads();
    }
    // ---- raw -> XY[1] transpose (build acc region is dead now) ----
    {
        int n = t >> 2, f0 = (t & 3) * 4;
        float4 v4 = *(const float4*)&raw[((size_t)(g * 256 + n)) * 16 + f0];
        XY[1][(f0 + 0) * XPCH + n] = (f16)v4.x;
        XY[1][(f0 + 1) * XPCH + n] = (f16)v4.y;
        XY[1][(f0 + 2) * XPCH + n] = (f16)v4.z;
        XY[1][(f0 + 3) * XPCH + n] = (f16)v4.w;
    }
    __syncthreads();
    // ---------------- encoder convs (start cur=1: XY[1] holds rawT) ----------
    const int woff[4] = {0, 2048, 6144, 10240};
    const float* bptr[4] = {b1, b2, b3, b4};
    int cur = 1;
#pragma unroll
    for (int c = 0; c < 4; ++c) {
        const int MT = (c == 0) ? 1 : 4;
        const int K2 = (c == 0) ? 32 : 64;
        const f16* wt = wb + woff[c];
        if (t < 64) bs[t] = bptr[c][t];
        for (int idx = t * 4; idx < 64 * K2; idx += 4096) {
            int of = idx / K2, k = idx % K2;
            *(f16x4*)&Ws[of * PCH + k] = *(const f16x4*)&wt[of * K2 + k];
        }
        // stage 1: agg^T = X^T . Ahat^T, B-operand entirely from registers.
        f32x4 acc1[4] = {};
#pragma unroll
        for (int kc = 0; kc < 4; ++kc)
#pragma unroll
            for (int ks = 0; ks < 2; ++ks) {
                f16x8 b = bfrag[kc * 2 + ks];
#pragma unroll
                for (int mt = 0; mt < MT; ++mt) {
                    f16x8 a = *(const f16x8*)&XY[cur][(mt * 16 + m16) * XPCH + kc * 64 + ks * 32 + q * 8];
                    acc1[mt] = __builtin_amdgcn_mfma_f32_16x16x32_f16(a, b, acc1[mt], 0, 0, 0);
                }
            }
        // stage 2: (agg)@W via Pt = As[wg]
        {
            f16* Pt = As[wg];
            if (MT == 1)
                for (int idx = tl; idx < 1024; idx += 256)
                    Pt[(idx >> 4) * PCH + 16 + (idx & 15)] = (f16)0.f;
#pragma unroll
            for (int mt = 0; mt < MT; ++mt) {
                f16x4 v = {(f16)acc1[mt][0], (f16)acc1[mt][1],
                           (f16)acc1[mt][2], (f16)acc1[mt][3]};
                *(f16x4*)&Pt[(wl * 16 + m16) * PCH + mt * 16 + q * 4] = v;
            }
            __syncthreads();
            f32x4 acc2[4] = {};
#pragma unroll
            for (int ks = 0; ks < K2 / 32; ++ks) {
                f16x8 b = *(const f16x8*)&Pt[(wl * 16 + m16) * PCH + ks * 32 + q * 8];
#pragma unroll
                for (int mt = 0; mt < 4; ++mt) {
                    f16x8 a = *(const f16x8*)&Ws[(mt * 16 + m16) * PCH + ks * 32 + q * 8];
                    acc2[mt] = __builtin_amdgcn_mfma_f32_16x16x32_f16(a, b, acc2[mt], 0, 0, 0);
                }
            }
            f16* Yf = XY[cur ^ 1];
#pragma unroll
            for (int mt = 0; mt < 4; ++mt)
#pragma unroll
                for (int r = 0; r < 4; ++r) {
                    int of = mt * 16 + q * 4 + r;
                    float v = fmaxf(acc2[mt][r] + bs[of], 0.f);
                    Yf[of * XPCH + wg * 64 + wl * 16 + m16] = (f16)v;
                }
        }
        __syncthreads();
        cur ^= 1;
        const f16* Yv = XY[cur];
        // node-major outputs: [g*256+n][of] (transposed write, fully coalesced)
        if (c != 1) {
            f16* hb = (c == 0) ? h1b : (c == 2) ? h3b : h4b;
            int n = (t >> 2) & 255, of0 = (t & 3) * 16;
            f16x8 v0, v1;
            for (int i = 0; i < 8; ++i) v0[i] = Yv[(of0 + i) * XPCH + n];
            for (int i = 0; i < 8; ++i) v1[i] = Yv[(of0 + 8 + i) * XPCH + n];
            size_t base = ((size_t)(g * 256 + n)) * 64 + of0;
            *(f16x8*)&hb[base] = v0;
            *(f16x8*)&hb[base + 8] = v1;
        }
    }
}

// ------------------------------------- mu/logvar MFMA split-K GEMM -----------
// 32-way split-K. Grid 512 = 32kc x 4jt x 4gt.
#define BKP 136
__global__ __launch_bounds__(256) void k_mulv_mfma(const f16* __restrict__ h4b,
                                                   const f16* __restrict__ WT,
                                                   float* __restrict__ part) {
    __shared__ f16 Ab[64 * BKP];
    __shared__ f16 Bb[64 * BKP];
    const int bx = blockIdx.x;
    const int kc = bx & 31, jt = (bx >> 5) & 3, gt = bx >> 7;
    const int t = threadIdx.x;
    const int w = t >> 6, lane = t & 63;
    const int m16 = lane & 15, q = lane >> 4;
    f32x4 acc[4] = {};
    const int k0base = kc * 512;
    for (int ks = 0; ks < 4; ++ks) {
        const int k0 = k0base + ks * 128;
#pragma unroll
        for (int p = 0; p < 4; ++p) {
            int oct = t + p * 256;
            int r = oct >> 4, c8 = oct & 15;
            *(f16x8*)&Ab[r * BKP + c8 * 8] =
                *(const f16x8*)&h4b[(size_t)(gt * 64 + r) * KFLAT + k0 + c8 * 8];
            *(f16x8*)&Bb[r * BKP + c8 * 8] =
                *(const f16x8*)&WT[(size_t)(jt * 64 + r) * KFLAT + k0 + c8 * 8];
        }
        __syncthreads();
#pragma unroll
        for (int kk = 0; kk < 4; ++kk) {
            f16x8 a = *(const f16x8*)&Ab[(w * 16 + m16) * BKP + kk * 32 + q * 8];
#pragma unroll
            for (int nt = 0; nt < 4; ++nt) {
                f16x8 b = *(const f16x8*)&Bb[(nt * 16 + m16) * BKP + kk * 32 + q * 8];
                acc[nt] = __builtin_amdgcn_mfma_f32_16x16x32_f16(a, b, acc[nt], 0, 0, 0);
            }
        }
        __syncthreads();
    }
    const int pb = kc << 16;
#pragma unroll
    for (int nt = 0; nt < 4; ++nt) {
        const int jj = jt * 64 + nt * 16 + m16;
#pragma unroll
        for (int r = 0; r < 4; ++r) {
            int g = gt * 64 + w * 16 + q * 4 + r;
            part[pb + g * 256 + jj] = acc[nt][r];
        }
    }
}

// reduce partials -> mu, logvar (d_out) and z (f16).
__global__ __launch_bounds__(256) void k_reduce(const float* __restrict__ part,
                                                const float* __restrict__ bmu,
                                                const float* __restrict__ blv,
                                                const float* __restrict__ eps,
                                                float* __restrict__ out,
                                                f16* __restrict__ zb) {
    const int idx = blockIdx.x * 256 + threadIdx.x;
    const int g = idx >> 7, j = idx & 127;
    float mu = bmu[j], lv = blv[j];
    for (int kc = 0; kc < 32; ++kc) {
        mu += part[(kc << 16) + g * 256 + j];
        lv += part[(kc << 16) + g * 256 + 128 + j];
    }
    out[1048576 + idx] = mu;
    out[1048576 + 32768 + idx] = lv;
    zb[idx] = (f16)(mu + eps[idx] * expf(0.5f * lv));
}

// ------- latb[g*16384 + jn] = (z @ Wdec)[g][jn] + bdec[jn]  (node-major) -----
// Swapped operands: A = Wdecn rows (jn), B = z rows (g) -> lane-fast dim is jn
// -> contiguous f16x4 stores. Grid 512 = 4gt x 128 jn-tiles.
#define DKP 136
__global__ __launch_bounds__(256) void k_decgemm(const f16* __restrict__ zb,
                                                 const f16* __restrict__ Wdecn,
                                                 const float* __restrict__ bdec,
                                                 f16* __restrict__ latb) {
    __shared__ f16 Wn[128 * DKP];
    __shared__ f16 Zt[64 * DKP];
    const int gt = blockIdx.x >> 7, jt = blockIdx.x & 127;
    const int t = threadIdx.x, w = t >> 6, lane = t & 63, m16 = lane & 15, q = lane >> 4;
    for (int idx = t * 8; idx < 128 * 128; idx += 2048) {
        int r = idx >> 7, c = idx & 127;
        *(f16x8*)&Wn[r * DKP + c] = *(const f16x8*)&Wdecn[((size_t)(jt * 128 + r)) * ZD + c];
    }
    for (int idx = t * 8; idx < 64 * 128; idx += 2048) {
        int r = idx >> 7, c = idx & 127;
        *(f16x8*)&Zt[r * DKP + c] = *(const f16x8*)&zb[(gt * 64 + r) * ZD + c];
    }
    __syncthreads();
    f32x4 acc[2][4] = {};
#pragma unroll
    for (int kk = 0; kk < 4; ++kk) {
        f16x8 a0 = *(const f16x8*)&Wn[(w * 32 + m16) * DKP + kk * 32 + q * 8];
        f16x8 a1 = *(const f16x8*)&Wn[(w * 32 + 16 + m16) * DKP + kk * 32 + q * 8];
#pragma unroll
        for (int nt = 0; nt < 4; ++nt) {
            f16x8 b = *(const f16x8*)&Zt[(nt * 16 + m16) * DKP + kk * 32 + q * 8];
            acc[0][nt] = __builtin_amdgcn_mfma_f32_16x16x32_f16(a0, b, acc[0][nt], 0, 0, 0);
            acc[1][nt] = __builtin_amdgcn_mfma_f32_16x16x32_f16(a1, b, acc[1][nt], 0, 0, 0);
        }
    }
#pragma unroll
    for (int mi = 0; mi < 2; ++mi) {
        int jn0 = jt * 128 + w * 32 + mi * 16 + q * 4;
        float4 bd = *(const float4*)&bdec[jn0];
#pragma unroll
        for (int nt = 0; nt < 4; ++nt) {
            int g = gt * 64 + nt * 16 + m16;
            f16x4 v = {(f16)(acc[mi][nt][0] + bd.x), (f16)(acc[mi][nt][1] + bd.y),
                       (f16)(acc[mi][nt][2] + bd.z), (f16)(acc[mi][nt][3] + bd.w)};
            *(f16x4*)&latb[(size_t)g * KFLAT + jn0] = v;
        }
    }
}

// ----------------- fused decoder: catgemm, g1, g2, out GEMM ------------------
#define WPCH 240   // Wg1s pitch (f16): 480 B rows, 16B-aligned fragments
__global__ __launch_bounds__(1024) void k_decfused(const f16* __restrict__ latb,
                                                   const f16* __restrict__ h1b,
                                                   const f16* __restrict__ h3b,
                                                   const f16* __restrict__ Ahat,
                                                   const f16* __restrict__ wb,
                                                   const float* __restrict__ bg1,
                                                   const float* __restrict__ bg2,
                                                   const float* __restrict__ Wout,
                                                   const float* __restrict__ bout,
                                                   const float* __restrict__ raw,
                                                   float* __restrict__ out) {
    __shared__ f16 XY[2][64 * XPCH];   // 67.6 KB
    __shared__ f16 As[4][64 * PCH];    // 36.9 KB, used only as Pt
    __shared__ f16 Ws[64 * PCH];       // 9.2 KB (Wg2)
    __shared__ f16 Wg1s[64 * WPCH];    // 30 KB (whole Wg1^T, staged once)
    __shared__ float WL[1024];
    __shared__ float bs1[64], bs2[64];
    const int g = blockIdx.x, t = threadIdx.x;
    const int wg = t >> 8, wl = (t >> 6) & 3;
    const int lane = t & 63, m16 = lane & 15, q = lane >> 4;
    const int n = wg * 64 + wl * 16 + m16;         // output node owned (B-col)
    const f16* wg1t = wb + 18432;
    const f16* wg2t = wb + 14336;
    // register-resident Ahat B-fragments (conv-invariant, phases 2&3)
    f16x8 bfrag[8];
    {
        const f16* ab = Ahat + (((size_t)(g * 256 + n)) << 8) + q * 8;
#pragma unroll
        for (int kc = 0; kc < 4; ++kc)
#pragma unroll
            for (int ks = 0; ks < 2; ++ks)
                bfrag[kc * 2 + ks] = *(const f16x8*)&ab[kc * 64 + ks * 32];
    }
    // cat^T B-fragments: node-major buffers -> each octet is ONE f16x8 load.
    const size_t nb = (size_t)(g * 256 + n);
    f16x8 bcat[7];
#pragma unroll
    for (int kc = 0; kc < 7; ++kc) {
        int k0 = kc * 32 + q * 8;
        f16x8 v = {};
        if (k0 < 64) {
            v = *(const f16x8*)&latb[nb * 64 + k0];
        } else if (k0 < 80) {
            const float* rpf = raw + nb * 16 + (k0 - 64);
#pragma unroll
            for (int i = 0; i < 8; ++i) v[i] = (f16)rpf[i];
        } else if (k0 < 144) {
            v = *(const f16x8*)&h1b[nb * 64 + (k0 - 80)];
        } else if (k0 < 208) {
            v = *(const f16x8*)&h3b[nb * 64 + (k0 - 144)];
        }
        bcat[kc] = v;
    }
    if (t < 64) bs1[t] = bg1[t];
    else if (t < 128) bs2[t - 64] = bg2[t - 64];
    // ---- phase 1: t^T = Wg1t . cat^T -> XY[0] (1 barrier, B from registers)
    {
        for (int idx = t; idx < 3584; idx += 1024) {       // 64 rows x 56 segs
            int of = idx / 56, sg = idx % 56;
            *(f16x4*)&Wg1s[of * WPCH + sg * 4] = *(const f16x4*)&wg1t[of * 224 + sg * 4];
        }
        __syncthreads();
        f32x4 acc[4] = {};
#pragma unroll
        for (int kc = 0; kc < 7; ++kc) {
            f16x8 b = bcat[kc];
#pragma unroll
            for (int mt = 0; mt < 4; ++mt) {
                f16x8 a = *(const f16x8*)&Wg1s[(mt * 16 + m16) * WPCH + kc * 32 + q * 8];
                acc[mt] = __builtin_amdgcn_mfma_f32_16x16x32_f16(a, b, acc[mt], 0, 0, 0);
            }
        }
#pragma unroll
        for (int mt = 0; mt < 4; ++mt)
#pragma unroll
            for (int r = 0; r < 4; ++r)
                XY[0][(mt * 16 + q * 4 + r) * XPCH + n] = (f16)acc[mt][r];
        __syncthreads();
    }
    // ---- phase 2: x1 = relu(Ahat @ t + bg1) -> XY[1] (B from registers)
    {
        f32x4 acc1[4] = {};
#pragma unroll
        for (int kc = 0; kc < 4; ++kc)
#pragma unroll
            for (int ks = 0; ks < 2; ++ks) {
                f16x8 b = bfrag[kc * 2 + ks];
#pragma unroll
                for (int mt = 0; mt < 4; ++mt) {
                    f16x8 a = *(const f16x8*)&XY[0][(mt * 16 + m16) * XPCH + kc * 64 + ks * 32 + q * 8];
                    acc1[mt] = __builtin_amdgcn_mfma_f32_16x16x32_f16(a, b, acc1[mt], 0, 0, 0);
                }
            }
#pragma unroll
        for (int mt = 0; mt < 4; ++mt)
#pragma unroll
            for (int r = 0; r < 4; ++r) {
                int of = mt * 16 + q * 4 + r;
                float v = fmaxf(acc1[mt][r] + bs1[of], 0.f);
                XY[1][of * XPCH + n] = (f16)v;
            }
        __syncthreads();
    }
    // ---- phase 3: x2 = relu((Ahat @ x1)@Wg2 + bg2) -> XY[0]
    {
        for (int idx = t * 4; idx < 4096; idx += 4096) {
            int of = idx >> 6, k = idx & 63;
            *(f16x4*)&Ws[of * PCH + k] = *(const f16x4*)&wg2t[of * 64 + k];
        }
        f32x4 acc1[4] = {};
#pragma unroll
        for (int kc = 0; kc < 4; ++kc)
#pragma unroll
            for (int ks = 0; ks < 2; ++ks) {
                f16x8 b = bfrag[kc * 2 + ks];
#pragma unroll
                for (int mt = 0; mt < 4; ++mt) {
                    f16x8 a = *(const f16x8*)&XY[1][(mt * 16 + m16) * XPCH + kc * 64 + ks * 32 + q * 8];
                    acc1[mt] = __builtin_amdgcn_mfma_f32_16x16x32_f16(a, b, acc1[mt], 0, 0, 0);
                }
            }
        f16* Pt = As[wg];
#pragma unroll
        for (int mt = 0; mt < 4; ++mt) {
            f16x4 v = {(f16)acc1[mt][0], (f16)acc1[mt][1],
                       (f16)acc1[mt][2], (f16)acc1[mt][3]};
            *(f16x4*)&Pt[(wl * 16 + m16) * PCH + mt * 16 + q * 4] = v;
        }
        __syncthreads();
        f32x4 acc2[4] = {};
#pragma unroll
        for (int ks = 0; ks < 2; ++ks) {
            f16x8 b = *(const f16x8*)&Pt[(wl * 16 + m16) * PCH + ks * 32 + q * 8];
#pragma unroll
            for (int mt = 0; mt < 4; ++mt) {
                f16x8 a = *(const f16x8*)&Ws[(mt * 16 + m16) * PCH + ks * 32 + q * 8];
                acc2[mt] = __builtin_amdgcn_mfma_f32_16x16x32_f16(a, b, acc2[mt], 0, 0, 0);
            }
        }
#pragma unroll
        for (int mt = 0; mt < 4; ++mt)
#pragma unroll
            for (int r = 0; r < 4; ++r) {
                int of = mt * 16 + q * 4 + r;
                float v = fmaxf(acc2[mt][r] + bs2[of], 0.f);
                XY[0][of * XPCH + n] = (f16)v;
            }
        __syncthreads();
    }
    // ---- phase 4: recon = x2^T @ Wout + bout (col0 = raw)
    {
        WL[t & 1023] = Wout[t & 1023];
        __syncthreads();
        int nn = t & 255, og = t >> 8;
        float acc4[4];
        for (int j = 0; j < 4; ++j) acc4[j] = bout[og * 4 + j];
#pragma unroll 4
        for (int f = 0; f < 64; ++f) {
            float xv = (float)XY[0][f * XPCH + nn];
            for (int j = 0; j < 4; ++j) acc4[j] += xv * WL[f * 16 + og * 4 + j];
        }
        size_t ob = ((size_t)(g * 256 + nn)) * 16 + og * 4;
        if (og == 0) acc4[0] = raw[((size_t)(g * 256 + nn)) * 16];
        *(float4*)&out[ob] = make_float4(acc4[0], acc4[1], acc4[2], acc4[3]);
    }
}

// ----------------------------------------------------------------- launch ----
extern "C" void kernel_launch(void* const* d_in, const int* in_sizes, int n_in,
                              void* d_out, int out_size, void* d_ws, size_t ws_size,
                              hipStream_t stream) {
    const float* raw  = (const float*)d_in[0];
    const int*   src  = (const int*)d_in[1];
    const int*   dst  = (const int*)d_in[2];
    const float* eps  = (const float*)d_in[3];
    const float* W1   = (const float*)d_in[4];
    const float* b1   = (const float*)d_in[5];
    const float* W2   = (const float*)d_in[6];
    const float* b2   = (const float*)d_in[7];
    const float* W3   = (const float*)d_in[8];
    const float* b3   = (const float*)d_in[9];
    const float* W4   = (const float*)d_in[10];
    const float* b4   = (const float*)d_in[11];
    const float* Wmu  = (const float*)d_in[12];
    const float* bmu  = (const float*)d_in[13];
    const float* Wlv  = (const float*)d_in[14];
    const float* blv  = (const float*)d_in[15];
    const float* Wdec = (const float*)d_in[16];
    const float* bdec = (const float*)d_in[17];
    const float* Wg1  = (const float*)d_in[18];
    const float* bg1  = (const float*)d_in[19];
    const float* Wg2  = (const float*)d_in[20];
    const float* bg2  = (const float*)d_in[21];
    const float* Wout = (const float*)d_in[22];
    const float* bout = (const float*)d_in[23];
    float* out = (float*)d_out;

    // workspace carve-up (~85 MB)
    char* p = (char*)d_ws;
    f16* Ahat  = (f16*)p;             p += (size_t)NG * 256 * 256 * 2;   // 32 MB
    f16* WT    = (f16*)p;             p += (size_t)256 * KFLAT * 2;      // 8 MB
    f16* Wdecn = (f16*)p;             p += (size_t)KFLAT * ZD * 2;       // 4 MB
    f16* wb    = (f16*)p;             p += 65536;                        // 64 KB
    f16* zb    = (f16*)p;             p += 65536;                        // 64 KB
    f16* h1b   = (f16*)p;             p += (size_t)NN * 64 * 2;          // 8 MB
    f16* h3b   = (f16*)p;             p += (size_t)NN * 64 * 2;
    f16* h4b   = (f16*)p;             p += (size_t)NN * 64 * 2;
    f16* latb  = (f16*)p;             p += (size_t)NN * 64 * 2;
    float* part = (float*)p;          p += (size_t)32 * 65536 * 4;       // 8 MB

    // one-time weight casts/transposes
    k_prep<<<6272, 256, 0, stream>>>(W1, W2, W3, W4, Wg2, Wg1, Wmu, Wlv, Wdec,
                                     wb, WT, Wdecn);

    // encoder (1 launch: Ahat build + raw transpose + conv1..conv4)
    k_enc<<<NG, 1024, 0, stream>>>(src, dst, raw, wb, b1, b2, b3, b4,
                                   Ahat, h1b, h3b, h4b);

    // bottleneck: mu/logvar -> z -> latent
    k_mulv_mfma<<<512, 256, 0, stream>>>(h4b, WT, part);
    k_reduce<<<128, 256, 0, stream>>>(part, bmu, blv, eps, out, zb);
    k_decgemm<<<512, 256, 0, stream>>>(zb, Wdecn, bdec, latb);

    // decoder (1 launch: catgemm + g1 + g2 + out GEMM fused)
    k_decfused<<<NG, 1024, 0, stream>>>(latb, h1b, h3b, Ahat, wb,
                                        bg1, bg2, Wout, bout, raw, out);
}